// Round 3
// baseline (279.431 us; speedup 1.0000x reference)
//
#include <hip/hip_runtime.h>
#include <hip/hip_bf16.h>

// ---- types ----
typedef __bf16 bf16x8 __attribute__((ext_vector_type(8)));
typedef __bf16 bf16x4 __attribute__((ext_vector_type(4)));
typedef float  f32x4  __attribute__((ext_vector_type(4)));

#define MFMA16(a, b, c) __builtin_amdgcn_mfma_f32_16x16x32_bf16((a), (b), (c), 0, 0, 0)

// Problem constants
#define BATCH 16
#define SEQ   1024
#define VD    1024
#define TD    768
#define HDIM  512
#define MROWS (BATCH * SEQ)   // 16384

typedef __attribute__((address_space(1))) const unsigned int gas_uint;
typedef __attribute__((address_space(3))) unsigned int las_uint;

__device__ __forceinline__ void async_copy16(const void* g, void* l) {
    __builtin_amdgcn_global_load_lds((gas_uint*)g, (las_uint*)l, 16, 0, 0);
}

// ---------------------------------------------------------------------------
// W fp32 -> bf16 pre-convert (tiny: 1.75 MB out)
// ---------------------------------------------------------------------------
__global__ __launch_bounds__(256) void wconv_kernel(const float* __restrict__ Wv,
                                                    const float* __restrict__ Wt,
                                                    __bf16* __restrict__ Wbv,
                                                    __bf16* __restrict__ Wbt) {
    const int NV = (HDIM * VD) / 4;   // 131072 float4 chunks
    const int NT = (HDIM * TD) / 4;   // 98304
    int i = blockIdx.x * 256 + threadIdx.x;
    const float* src;
    __bf16* dst;
    if (i < NV) { src = Wv; dst = Wbv; }
    else        { i -= NV; if (i >= NT) return; src = Wt; dst = Wbt; }
    const float4 x = reinterpret_cast<const float4*>(src)[i];
    bf16x4 p = {(__bf16)x.x, (__bf16)x.y, (__bf16)x.z, (__bf16)x.w};
    reinterpret_cast<bf16x4*>(dst)[i] = p;
}

// ---------------------------------------------------------------------------
// Projection GEMM (NT): block = 128 rows x 512 cols (ALL of H). 512 threads,
// 8 waves as 2(row)x4(col), wave tile 64x128 (4x8 MFMA 16x16x32).
// - X staged via LDS (double-buffered, padded stride, register prefetch,
//   ONE barrier per k-step), fp32->bf16 cvt fused into staging.
// - W fragments read directly from global bf16 (L1/L2-resident, no LDS).
// - Epilogue: +bias, bf16 store, fused row-norm^2 via shfl+atomicAdd.
// blockIdx.y selects visual / text.
// ---------------------------------------------------------------------------
#define APAD 40   // padded k-stride (elements); 80B rows keep 16B alignment

__global__ __launch_bounds__(512, 2) void proj_kernel(
    const float* __restrict__ Xv, const __bf16* __restrict__ Wbv, const float* __restrict__ bv_,
    const float* __restrict__ Xt, const __bf16* __restrict__ Wbt, const float* __restrict__ bt_,
    __bf16* __restrict__ vout, __bf16* __restrict__ tout,
    float* __restrict__ vn2, float* __restrict__ tn2)
{
    const float* X; const __bf16* Wb; const float* bias; __bf16* out; float* n2; int K;
    if (blockIdx.y == 0) { X = Xv; Wb = Wbv; bias = bv_; out = vout; n2 = vn2; K = VD; }
    else                 { X = Xt; Wb = Wbt; bias = bt_; out = tout; n2 = tn2; K = TD; }

    __shared__ __bf16 As[2][128 * APAD];

    const int m0   = blockIdx.x * 128;
    const int tid  = threadIdx.x;
    const int lane = tid & 63;
    const int wave = tid >> 6;
    const int wr   = wave & 1;    // row half (0..1)
    const int wc   = wave >> 1;   // col quarter (0..3)
    const int fr   = lane & 15;
    const int fq   = lane >> 4;

    // staging map: thread handles float4 chunks f = tid and tid+512 (of 1024)
    int srow[2], sc4[2];
#pragma unroll
    for (int it = 0; it < 2; ++it) {
        const int f = tid + it * 512;
        srow[it] = f >> 3;     // 8 float4 per 32-col row
        sc4[it]  = f & 7;
    }

    // B fragment base: col = wc*128 + tn*16 + fr, k-offset fq*8
    const __bf16* wbase = Wb + (size_t)(wc * 128 + fr) * K + fq * 8;

    f32x4 acc[4][8] = {};

    // ---- prologue: stage tile 0 ----
    float4 ra[2];
#pragma unroll
    for (int it = 0; it < 2; ++it)
        ra[it] = *reinterpret_cast<const float4*>(&X[(size_t)(m0 + srow[it]) * K + sc4[it] * 4]);
#pragma unroll
    for (int it = 0; it < 2; ++it) {
        bf16x4 p = {(__bf16)ra[it].x, (__bf16)ra[it].y, (__bf16)ra[it].z, (__bf16)ra[it].w};
        *reinterpret_cast<bf16x4*>(&As[0][srow[it] * APAD + sc4[it] * 4]) = p;
    }
    __syncthreads();

    const int nk = K >> 5;
    for (int ki = 0; ki < nk; ++ki) {
        const int kk = ki << 5;
        // register prefetch of X tile k+1 (latency overlaps MFMA below)
        const bool more = (ki + 1) < nk;
        if (more) {
#pragma unroll
            for (int it = 0; it < 2; ++it)
                ra[it] = *reinterpret_cast<const float4*>(&X[(size_t)(m0 + srow[it]) * K + kk + 32 + sc4[it] * 4]);
        }

        // B fragments straight from global (bf16, L1/L2-hot)
        bf16x8 b[8];
#pragma unroll
        for (int tn = 0; tn < 8; ++tn)
            b[tn] = *reinterpret_cast<const bf16x8*>(wbase + (size_t)tn * 16 * K + kk);

        // A fragments from LDS
        const __bf16* Ab = As[ki & 1];
        bf16x8 a[4];
#pragma unroll
        for (int tm = 0; tm < 4; ++tm)
            a[tm] = *reinterpret_cast<const bf16x8*>(&Ab[(wr * 64 + tm * 16 + fr) * APAD + fq * 8]);

#pragma unroll
        for (int tm = 0; tm < 4; ++tm)
#pragma unroll
            for (int tn = 0; tn < 8; ++tn)
                acc[tm][tn] = MFMA16(a[tm], b[tn], acc[tm][tn]);

        if (more) {
            __bf16* Aw = As[(ki + 1) & 1];
#pragma unroll
            for (int it = 0; it < 2; ++it) {
                bf16x4 p = {(__bf16)ra[it].x, (__bf16)ra[it].y, (__bf16)ra[it].z, (__bf16)ra[it].w};
                *reinterpret_cast<bf16x4*>(&Aw[srow[it] * APAD + sc4[it] * 4]) = p;
            }
            __syncthreads();
        }
    }

    // ---- epilogue: +bias, bf16 store, fused row-norm^2 ----
    float bc[8];
#pragma unroll
    for (int tn = 0; tn < 8; ++tn)
        bc[tn] = bias[wc * 128 + tn * 16 + fr];

#pragma unroll
    for (int tm = 0; tm < 4; ++tm) {
        const int rowb = m0 + wr * 64 + tm * 16 + fq * 4;
#pragma unroll
        for (int r = 0; r < 4; ++r) {
            float s = 0.f;
#pragma unroll
            for (int tn = 0; tn < 8; ++tn) {
                const float e = acc[tm][tn][r] + bc[tn];
                out[(size_t)(rowb + r) * HDIM + wc * 128 + tn * 16 + fr] = (__bf16)e;
                s = fmaf(e, e, s);
            }
            // reduce over the 16 fr-lanes (stays within fq group)
            s += __shfl_xor(s, 1);
            s += __shfl_xor(s, 2);
            s += __shfl_xor(s, 4);
            s += __shfl_xor(s, 8);
            if (fr == 0) atomicAdd(&n2[rowb + r], s);
        }
    }
}

// ---------------------------------------------------------------------------
// Batched dots GEMM (NT): out[b][i][j] = v.t / max(sqrt(vn2_i*tn2_j), eps)
// 128x128 tile, K=512, bf16 inputs staged via global_load_lds (16B/lane).
// ---------------------------------------------------------------------------
__global__ __launch_bounds__(256) void dots_kernel(const __bf16* __restrict__ v,
                                                   const __bf16* __restrict__ t,
                                                   const float* __restrict__ vn2,
                                                   const float* __restrict__ tn2,
                                                   float* __restrict__ out) {
    __shared__ __bf16 As[128 * 32];
    __shared__ __bf16 Bs[128 * 32];

    const int b  = blockIdx.z;
    const int j0 = blockIdx.x * 128;
    const int i0 = blockIdx.y * 128;
    const __bf16* vb = v + (size_t)b * SEQ * HDIM;
    const __bf16* tb = t + (size_t)b * SEQ * HDIM;

    const int tid  = threadIdx.x;
    const int lane = tid & 63;
    const int wave = tid >> 6;
    const int wr   = wave >> 1;
    const int wc   = wave & 1;
    const int fr   = lane & 15;
    const int fq   = lane >> 4;

    f32x4 acc[4][4] = {};

    for (int kk = 0; kk < HDIM; kk += 32) {
#pragma unroll
        for (int s = 0; s < 2; ++s) {
            const int c    = (wave * 2 + s) * 64 + lane;
            const int row  = c >> 2;
            const int part = c & 3;
            async_copy16(&vb[(size_t)(i0 + row) * HDIM + kk + part * 8],
                         &As[(wave * 2 + s) * 512]);
            async_copy16(&tb[(size_t)(j0 + row) * HDIM + kk + part * 8],
                         &Bs[(wave * 2 + s) * 512]);
        }
        __syncthreads();

        bf16x8 a[4], bfr[4];
#pragma unroll
        for (int t_ = 0; t_ < 4; ++t_) {
            a[t_]   = *reinterpret_cast<const bf16x8*>(&As[(wr * 64 + t_ * 16 + fr) * 32 + fq * 8]);
            bfr[t_] = *reinterpret_cast<const bf16x8*>(&Bs[(wc * 64 + t_ * 16 + fr) * 32 + fq * 8]);
        }
#pragma unroll
        for (int tm = 0; tm < 4; ++tm)
#pragma unroll
            for (int tn_ = 0; tn_ < 4; ++tn_)
                acc[tm][tn_] = MFMA16(a[tm], bfr[tn_], acc[tm][tn_]);
        __syncthreads();
    }

    float vr2[16];
#pragma unroll
    for (int tm = 0; tm < 4; ++tm)
#pragma unroll
        for (int r = 0; r < 4; ++r)
            vr2[tm * 4 + r] = vn2[b * SEQ + i0 + wr * 64 + tm * 16 + fq * 4 + r];

    float* outb = out + ((size_t)b << 20);
#pragma unroll
    for (int tn_ = 0; tn_ < 4; ++tn_) {
        const int j     = j0 + wc * 64 + tn_ * 16 + fr;
        const float tj2 = tn2[b * SEQ + j];
#pragma unroll
        for (int tm = 0; tm < 4; ++tm) {
            const int ib = i0 + wr * 64 + tm * 16 + fq * 4;
#pragma unroll
            for (int r = 0; r < 4; ++r) {
                const float denom = fmaxf(sqrtf(vr2[tm * 4 + r] * tj2), 1e-8f);
                outb[(size_t)(ib + r) * SEQ + j] = acc[tm][tn_][r] * __builtin_amdgcn_rcpf(denom);
            }
        }
    }
}

// ---------------------------------------------------------------------------
extern "C" void kernel_launch(void* const* d_in, const int* in_sizes, int n_in,
                              void* d_out, int out_size, void* d_ws, size_t ws_size,
                              hipStream_t stream) {
    const float* Xv = (const float*)d_in[0];  // [16,1024,1024]
    const float* Xt = (const float*)d_in[1];  // [16,1024,768]
    const float* Wv = (const float*)d_in[2];  // [512,1024]
    const float* bv = (const float*)d_in[3];  // [512]
    const float* Wt = (const float*)d_in[4];  // [512,768]
    const float* bt = (const float*)d_in[5];  // [512]
    float* out = (float*)d_out;               // [16,1024,1024]

    char* ws = (char*)d_ws;
    size_t off = 0;
    __bf16* v   = (__bf16*)(ws + off); off += (size_t)MROWS * HDIM * 2;   // 16 MiB
    __bf16* t   = (__bf16*)(ws + off); off += (size_t)MROWS * HDIM * 2;   // 16 MiB
    __bf16* Wbv = (__bf16*)(ws + off); off += (size_t)HDIM * VD * 2;      // 1 MiB
    __bf16* Wbt = (__bf16*)(ws + off); off += (size_t)HDIM * TD * 2;      // 0.75 MiB
    float*  vn2 = (float*)(ws + off);  off += (size_t)MROWS * 4;          // 64 KiB
    float*  tn2 = (float*)(ws + off);  off += (size_t)MROWS * 4;          // 64 KiB

    // zero the norm accumulators (ws is poisoned 0xAA before every launch)
    hipMemsetAsync(vn2, 0, (size_t)2 * MROWS * 4, stream);

    // 0) W -> bf16
    wconv_kernel<<<896, 256, 0, stream>>>(Wv, Wt, Wbv, Wbt);

    // 1) projections + fused norms: grid (m-tiles=128, z=2), 512 threads
    proj_kernel<<<dim3(128, 2), 512, 0, stream>>>(Xv, Wbv, bv, Xt, Wbt, bt, v, t, vn2, tn2);

    // 2) batched dots + normalize (grid: 8x8 tiles x 16 batches)
    dots_kernel<<<dim3(8, 8, BATCH), 256, 0, stream>>>(v, t, vn2, tn2, out);
}

// Round 4
// 260.839 us; speedup vs baseline: 1.0713x; 1.0713x over previous
//
#include <hip/hip_runtime.h>
#include <hip/hip_bf16.h>

// ---- types ----
typedef __bf16 bf16x8 __attribute__((ext_vector_type(8)));
typedef __bf16 bf16x4 __attribute__((ext_vector_type(4)));
typedef float  f32x4  __attribute__((ext_vector_type(4)));

#define MFMA16(a, b, c) __builtin_amdgcn_mfma_f32_16x16x32_bf16((a), (b), (c), 0, 0, 0)

// Problem constants
#define BATCH 16
#define SEQ   1024
#define VD    1024
#define TD    768
#define HDIM  512
#define MROWS (BATCH * SEQ)   // 16384

typedef __attribute__((address_space(1))) const unsigned int gas_uint;
typedef __attribute__((address_space(3))) unsigned int las_uint;

__device__ __forceinline__ void async_copy16(const void* g, void* l) {
    // global -> LDS DMA, 16B/lane; LDS dest = wave-uniform base + lane*16
    __builtin_amdgcn_global_load_lds((gas_uint*)g, (las_uint*)l, 16, 0, 0);
}

// ---------------------------------------------------------------------------
// W fp32 -> bf16 pre-convert (tiny: 1.75 MB out)
// ---------------------------------------------------------------------------
__global__ __launch_bounds__(256) void wconv_kernel(const float* __restrict__ Wv,
                                                    const float* __restrict__ Wt,
                                                    __bf16* __restrict__ Wbv,
                                                    __bf16* __restrict__ Wbt) {
    const int NV = (HDIM * VD) / 4;
    const int NT = (HDIM * TD) / 4;
    int i = blockIdx.x * 256 + threadIdx.x;
    const float* src;
    __bf16* dst;
    if (i < NV) { src = Wv; dst = Wbv; }
    else        { i -= NV; if (i >= NT) return; src = Wt; dst = Wbt; }
    const float4 x = reinterpret_cast<const float4*>(src)[i];
    bf16x4 p = {(__bf16)x.x, (__bf16)x.y, (__bf16)x.z, (__bf16)x.w};
    reinterpret_cast<bf16x4*>(dst)[i] = p;
}

// ---------------------------------------------------------------------------
// Projection GEMM (NT), m97-style DMA staging:
//   C[M][512] = X[M][K] * W[512][K]^T + bias -> bf16, + fused row-norm^2.
// 128x128 tile, 256 threads (4 waves 2x2, wave 64x64, 4x4 MFMA 16x16x32).
// A tile staged as *fp32* via global_load_lds (16 KiB), cvt->bf16 fused into
// the LDS->fragment read. B tile staged as bf16 via global_load_lds (8 KiB).
// Chunk-XOR swizzle (applied on the GLOBAL source address, LDS side stays
// lane-linear as required) kills LDS read bank conflicts.
// Block-id swizzle co-locates the 4 n-tiles of the same rows on one XCD.
// ---------------------------------------------------------------------------
__global__ __launch_bounds__(256) void proj_kernel(
    const float* __restrict__ Xv, const __bf16* __restrict__ Wbv, const float* __restrict__ bv_,
    const float* __restrict__ Xt, const __bf16* __restrict__ Wbt, const float* __restrict__ bt_,
    __bf16* __restrict__ vout, __bf16* __restrict__ tout,
    float* __restrict__ vn2, float* __restrict__ tn2)
{
    // L = (m&7) + 8*( n + 4*( (m>>3) + 16*z ) )  -> same-m n-tiles share an XCD
    const int L     = blockIdx.x;
    const int mlow  = L & 7;
    const int n     = (L >> 3) & 3;
    const int mhigh = (L >> 5) & 15;
    const int z     = L >> 9;
    const int m0    = (mhigh * 8 + mlow) * 128;
    const int n0    = n * 128;

    const float* X; const __bf16* Wb; const float* bias; __bf16* out; float* n2; int K;
    if (z == 0) { X = Xv; Wb = Wbv; bias = bv_; out = vout; n2 = vn2; K = VD; }
    else        { X = Xt; Wb = Wbt; bias = bt_; out = tout; n2 = tn2; K = TD; }

    __shared__ float  As[128 * 32];   // fp32 A tile, chunk-swizzled
    __shared__ __bf16 Bs[128 * 32];   // bf16 B tile, chunk-swizzled

    const int tid  = threadIdx.x;
    const int lane = tid & 63;
    const int wave = tid >> 6;
    const int wr   = wave >> 1;
    const int wc   = wave & 1;
    const int fr   = lane & 15;
    const int fq   = lane >> 4;

    f32x4 acc[4][4] = {};

    const int nk = K >> 5;
    for (int ki = 0; ki < nk; ++ki) {
        const int kk = ki << 5;

        // ---- stage A: 1024 fp32 chunks (16B), slot c holds global chunk (c&7)^(r&7)
#pragma unroll
        for (int i = 0; i < 4; ++i) {
            const int c = i * 256 + tid;
            const int r = c >> 3;
            const int g = (c & 7) ^ (r & 7);
            async_copy16(&X[(size_t)(m0 + r) * K + kk + g * 4], &As[(c & ~63) * 4]);
        }
        // ---- stage B: 512 bf16 chunks, slot c holds global chunk (c&3)^(r&3)
#pragma unroll
        for (int i = 0; i < 2; ++i) {
            const int c = i * 256 + tid;
            const int r = c >> 2;
            const int g = (c & 3) ^ (r & 3);
            async_copy16(&Wb[(size_t)(n0 + r) * K + kk + g * 8], &Bs[(c & ~63) * 8]);
        }
        __syncthreads();

        // ---- fragments
        bf16x8 a[4], b[4];
#pragma unroll
        for (int tm = 0; tm < 4; ++tm) {
            const int r   = wr * 64 + tm * 16 + fr;
            const int key = r & 7;
            const f32x4 lo = *reinterpret_cast<const f32x4*>(&As[(r * 8 + ((fq * 2)     ^ key)) * 4]);
            const f32x4 hi = *reinterpret_cast<const f32x4*>(&As[(r * 8 + ((fq * 2 + 1) ^ key)) * 4]);
            bf16x8 av = {(__bf16)lo[0], (__bf16)lo[1], (__bf16)lo[2], (__bf16)lo[3],
                         (__bf16)hi[0], (__bf16)hi[1], (__bf16)hi[2], (__bf16)hi[3]};
            a[tm] = av;
        }
#pragma unroll
        for (int tn = 0; tn < 4; ++tn) {
            const int r = wc * 64 + tn * 16 + fr;
            b[tn] = *reinterpret_cast<const bf16x8*>(&Bs[(r * 4 + (fq ^ (r & 3))) * 8]);
        }
#pragma unroll
        for (int tm = 0; tm < 4; ++tm)
#pragma unroll
            for (int tn = 0; tn < 4; ++tn)
                acc[tm][tn] = MFMA16(a[tm], b[tn], acc[tm][tn]);
        __syncthreads();
    }

    // ---- epilogue: +bias, bf16 store, fused partial row-norm^2 ----
    float bc[4];
#pragma unroll
    for (int tn = 0; tn < 4; ++tn)
        bc[tn] = bias[n0 + wc * 64 + tn * 16 + fr];

#pragma unroll
    for (int tm = 0; tm < 4; ++tm) {
        const int rowb = m0 + wr * 64 + tm * 16 + fq * 4;
#pragma unroll
        for (int r = 0; r < 4; ++r) {
            float s = 0.f;
#pragma unroll
            for (int tn = 0; tn < 4; ++tn) {
                const float e = acc[tm][tn][r] + bc[tn];
                out[(size_t)(rowb + r) * HDIM + n0 + wc * 64 + tn * 16 + fr] = (__bf16)e;
                s = fmaf(e, e, s);
            }
            s += __shfl_xor(s, 1);
            s += __shfl_xor(s, 2);
            s += __shfl_xor(s, 4);
            s += __shfl_xor(s, 8);
            if (fr == 0) atomicAdd(&n2[rowb + r], s);
        }
    }
}

// ---------------------------------------------------------------------------
// Batched dots GEMM (NT): out[b][i][j] = v.t / max(sqrt(vn2_i*tn2_j), eps)
// 128x128 tile, K=512, bf16 via global_load_lds. Batch-colocating XCD swizzle.
// ---------------------------------------------------------------------------
__global__ __launch_bounds__(256) void dots_kernel(const __bf16* __restrict__ v,
                                                   const __bf16* __restrict__ t,
                                                   const float* __restrict__ vn2,
                                                   const float* __restrict__ tn2,
                                                   float* __restrict__ out) {
    __shared__ __bf16 As[128 * 32];
    __shared__ __bf16 Bs[128 * 32];

    // L = (b&7) + 8*( j + 8*( i + 8*(b>>3) ) )  -> same-batch blocks share an XCD
    const int L  = blockIdx.x;
    const int b  = (L & 7) + ((L >> 9) << 3);
    const int j0 = ((L >> 3) & 7) * 128;
    const int i0 = ((L >> 6) & 7) * 128;

    const __bf16* vb = v + (size_t)b * SEQ * HDIM;
    const __bf16* tb = t + (size_t)b * SEQ * HDIM;

    const int tid  = threadIdx.x;
    const int lane = tid & 63;
    const int wave = tid >> 6;
    const int wr   = wave >> 1;
    const int wc   = wave & 1;
    const int fr   = lane & 15;
    const int fq   = lane >> 4;

    f32x4 acc[4][4] = {};

    for (int kk = 0; kk < HDIM; kk += 32) {
#pragma unroll
        for (int s = 0; s < 2; ++s) {
            const int c    = (wave * 2 + s) * 64 + lane;
            const int row  = c >> 2;
            const int part = c & 3;
            async_copy16(&vb[(size_t)(i0 + row) * HDIM + kk + part * 8],
                         &As[(wave * 2 + s) * 512]);
            async_copy16(&tb[(size_t)(j0 + row) * HDIM + kk + part * 8],
                         &Bs[(wave * 2 + s) * 512]);
        }
        __syncthreads();

        bf16x8 a[4], bfr[4];
#pragma unroll
        for (int t_ = 0; t_ < 4; ++t_) {
            a[t_]   = *reinterpret_cast<const bf16x8*>(&As[(wr * 64 + t_ * 16 + fr) * 32 + fq * 8]);
            bfr[t_] = *reinterpret_cast<const bf16x8*>(&Bs[(wc * 64 + t_ * 16 + fr) * 32 + fq * 8]);
        }
#pragma unroll
        for (int tm = 0; tm < 4; ++tm)
#pragma unroll
            for (int tn_ = 0; tn_ < 4; ++tn_)
                acc[tm][tn_] = MFMA16(a[tm], bfr[tn_], acc[tm][tn_]);
        __syncthreads();
    }

    float vr2[16];
#pragma unroll
    for (int tm = 0; tm < 4; ++tm)
#pragma unroll
        for (int r = 0; r < 4; ++r)
            vr2[tm * 4 + r] = vn2[b * SEQ + i0 + wr * 64 + tm * 16 + fq * 4 + r];

    float* outb = out + ((size_t)b << 20);
#pragma unroll
    for (int tn_ = 0; tn_ < 4; ++tn_) {
        const int j     = j0 + wc * 64 + tn_ * 16 + fr;
        const float tj2 = tn2[b * SEQ + j];
#pragma unroll
        for (int tm = 0; tm < 4; ++tm) {
            const int ib = i0 + wr * 64 + tm * 16 + fq * 4;
#pragma unroll
            for (int r = 0; r < 4; ++r) {
                const float denom = fmaxf(sqrtf(vr2[tm * 4 + r] * tj2), 1e-8f);
                outb[(size_t)(ib + r) * SEQ + j] = acc[tm][tn_][r] * __builtin_amdgcn_rcpf(denom);
            }
        }
    }
}

// ---------------------------------------------------------------------------
extern "C" void kernel_launch(void* const* d_in, const int* in_sizes, int n_in,
                              void* d_out, int out_size, void* d_ws, size_t ws_size,
                              hipStream_t stream) {
    const float* Xv = (const float*)d_in[0];
    const float* Xt = (const float*)d_in[1];
    const float* Wv = (const float*)d_in[2];
    const float* bv = (const float*)d_in[3];
    const float* Wt = (const float*)d_in[4];
    const float* bt = (const float*)d_in[5];
    float* out = (float*)d_out;

    char* ws = (char*)d_ws;
    size_t off = 0;
    __bf16* v   = (__bf16*)(ws + off); off += (size_t)MROWS * HDIM * 2;
    __bf16* t   = (__bf16*)(ws + off); off += (size_t)MROWS * HDIM * 2;
    __bf16* Wbv = (__bf16*)(ws + off); off += (size_t)HDIM * VD * 2;
    __bf16* Wbt = (__bf16*)(ws + off); off += (size_t)HDIM * TD * 2;
    float*  vn2 = (float*)(ws + off);  off += (size_t)MROWS * 4;
    float*  tn2 = (float*)(ws + off);  off += (size_t)MROWS * 4;

    hipMemsetAsync(vn2, 0, (size_t)2 * MROWS * 4, stream);

    // 0) W -> bf16
    wconv_kernel<<<896, 256, 0, stream>>>(Wv, Wt, Wbv, Wbt);

    // 1) projections + fused norms: 1024 swizzled blocks (512 v + 512 t)
    proj_kernel<<<1024, 256, 0, stream>>>(Xv, Wbv, bv, Xt, Wbt, bt, v, t, vn2, tn2);

    // 2) batched dots + normalize: 1024 swizzled blocks
    dots_kernel<<<1024, 256, 0, stream>>>(v, t, vn2, tn2, out);
}

// Round 5
// 248.340 us; speedup vs baseline: 1.1252x; 1.0503x over previous
//
#include <hip/hip_runtime.h>
#include <hip/hip_bf16.h>

// ---- types ----
typedef __bf16 bf16x8 __attribute__((ext_vector_type(8)));
typedef __bf16 bf16x4 __attribute__((ext_vector_type(4)));
typedef float  f32x4  __attribute__((ext_vector_type(4)));

#define MFMA16(a, b, c) __builtin_amdgcn_mfma_f32_16x16x32_bf16((a), (b), (c), 0, 0, 0)

// Problem constants
#define BATCH 16
#define SEQ   1024
#define VD    1024
#define TD    768
#define HDIM  512
#define MROWS (BATCH * SEQ)   // 16384

typedef __attribute__((address_space(1))) const unsigned int gas_uint;
typedef __attribute__((address_space(3))) unsigned int las_uint;

__device__ __forceinline__ void async_copy16(const void* g, void* l) {
    // global -> LDS DMA, 16B/lane; LDS dest = wave-uniform base + lane*16
    __builtin_amdgcn_global_load_lds((gas_uint*)g, (las_uint*)l, 16, 0, 0);
}

// ---------------------------------------------------------------------------
// Stage one 128x64 bf16 tile (1024 x 16B chunks) via DMA with chunk-XOR
// swizzle applied on the GLOBAL side (LDS side must stay lane-linear).
// Row r holds its 8 chunks in slots permuted by r&7.
// ---------------------------------------------------------------------------
__device__ __forceinline__ void stage_tile_bf16(const __bf16* __restrict__ src,
                                                size_t ld, int row0, int k0,
                                                __bf16* __restrict__ buf, int tid) {
#pragma unroll
    for (int i = 0; i < 4; ++i) {
        const int c = i * 256 + tid;          // chunk slot 0..1023
        const int r = c >> 3;                 // row 0..127
        const int g = (c & 7) ^ (r & 7);      // swizzled global chunk
        async_copy16(&src[(size_t)(row0 + r) * ld + k0 + g * 8],
                     &buf[(c & ~63) * 8]);
    }
}

// fragment read: row r, k-half h (0/1), quad fq -> chunk (h*4+fq)^(r&7)
__device__ __forceinline__ bf16x8 frag_read(const __bf16* __restrict__ buf,
                                            int r, int h, int fq) {
    return *reinterpret_cast<const bf16x8*>(&buf[(r * 8 + ((h * 4 + fq) ^ (r & 7))) * 8]);
}

// ---------------------------------------------------------------------------
// Convert Xv, Xt, Wv, Wt fp32 -> bf16 in one streaming pass (~168 MB).
// ---------------------------------------------------------------------------
#define NC_XV (BATCH * SEQ * VD / 4)   // 4194304
#define NC_XT (BATCH * SEQ * TD / 4)   // 3145728
#define NC_WV (HDIM * VD / 4)          // 131072
#define NC_WT (HDIM * TD / 4)          // 98304
#define NC_TOTAL (NC_XV + NC_XT + NC_WV + NC_WT)

__global__ __launch_bounds__(256) void conv_kernel(
    const float* __restrict__ Xv, const float* __restrict__ Xt,
    const float* __restrict__ Wv, const float* __restrict__ Wt,
    __bf16* __restrict__ Xvb, __bf16* __restrict__ Xtb,
    __bf16* __restrict__ Wvb, __bf16* __restrict__ Wtb) {
    int i = blockIdx.x * 256 + threadIdx.x;
    if (i >= NC_TOTAL) return;
    const float* src;
    __bf16* dst;
    if (i < NC_XV)                     { src = Xv; dst = Xvb; }
    else if ((i -= NC_XV) < NC_XT)     { src = Xt; dst = Xtb; }
    else if ((i -= NC_XT) < NC_WV)     { src = Wv; dst = Wvb; }
    else { i -= NC_WV;                   src = Wt; dst = Wtb; }
    const float4 x = reinterpret_cast<const float4*>(src)[i];
    bf16x4 p = {(__bf16)x.x, (__bf16)x.y, (__bf16)x.z, (__bf16)x.w};
    reinterpret_cast<bf16x4*>(dst)[i] = p;
}

// ---------------------------------------------------------------------------
// Projection GEMM (NT), all-bf16, BK=64, DMA-prefetch double-buffer:
//   C[M][512] = X[M][K] * W[512][K]^T + bias -> bf16, + fused row-norm^2.
// 128x128 tile, 256 threads (4 waves 2x2, wave 64x64, 4x4 MFMA 16x16x32).
// K-loop: stage tile k+1 into buf^1 (DMA, overlaps compute), compute tile k,
// one barrier per step (drains prefetch after compute has covered latency).
// ---------------------------------------------------------------------------
__global__ __launch_bounds__(256) void proj_kernel(
    const __bf16* __restrict__ Xvb, const __bf16* __restrict__ Wvb, const float* __restrict__ bv_,
    const __bf16* __restrict__ Xtb, const __bf16* __restrict__ Wtb, const float* __restrict__ bt_,
    __bf16* __restrict__ vout, __bf16* __restrict__ tout,
    float* __restrict__ vn2, float* __restrict__ tn2)
{
    // L = mlow + 8*( n + 4*( mhigh + 16*z ) ) -> same-m n-tiles share an XCD
    const int L     = blockIdx.x;
    const int mlow  = L & 7;
    const int n     = (L >> 3) & 3;
    const int mhigh = (L >> 5) & 15;
    const int z     = L >> 9;
    const int m0    = (mhigh * 8 + mlow) * 128;
    const int n0    = n * 128;

    const __bf16* X; const __bf16* Wb; const float* bias; __bf16* out; float* n2; int K;
    if (z == 0) { X = Xvb; Wb = Wvb; bias = bv_; out = vout; n2 = vn2; K = VD; }
    else        { X = Xtb; Wb = Wtb; bias = bt_; out = tout; n2 = tn2; K = TD; }

    __shared__ __bf16 As[2][128 * 64];
    __shared__ __bf16 Bs[2][128 * 64];

    const int tid  = threadIdx.x;
    const int lane = tid & 63;
    const int wave = tid >> 6;
    const int wr   = wave >> 1;
    const int wc   = wave & 1;
    const int fr   = lane & 15;
    const int fq   = lane >> 4;

    f32x4 acc[4][4] = {};
    const int nk = K >> 6;   // 16 (v) / 12 (t)

    // prologue: stage tile 0
    stage_tile_bf16(X,  K, m0, 0, As[0], tid);
    stage_tile_bf16(Wb, K, n0, 0, Bs[0], tid);
    __syncthreads();

    for (int ki = 0; ki < nk; ++ki) {
        // prefetch tile k+1 (DMA overlaps the compute below)
        if (ki + 1 < nk) {
            const int kk = (ki + 1) << 6;
            stage_tile_bf16(X,  K, m0, kk, As[(ki + 1) & 1], tid);
            stage_tile_bf16(Wb, K, n0, kk, Bs[(ki + 1) & 1], tid);
        }
        const __bf16* Ab = As[ki & 1];
        const __bf16* Bb = Bs[ki & 1];
#pragma unroll
        for (int h = 0; h < 2; ++h) {
            bf16x8 a[4], b[4];
#pragma unroll
            for (int tm = 0; tm < 4; ++tm)
                a[tm] = frag_read(Ab, wr * 64 + tm * 16 + fr, h, fq);
#pragma unroll
            for (int tn = 0; tn < 4; ++tn)
                b[tn] = frag_read(Bb, wc * 64 + tn * 16 + fr, h, fq);
#pragma unroll
            for (int tm = 0; tm < 4; ++tm)
#pragma unroll
                for (int tn = 0; tn < 4; ++tn)
                    acc[tm][tn] = MFMA16(a[tm], b[tn], acc[tm][tn]);
        }
        __syncthreads();
    }

    // epilogue: +bias, bf16 store, fused partial row-norm^2
    float bc[4];
#pragma unroll
    for (int tn = 0; tn < 4; ++tn)
        bc[tn] = bias[n0 + wc * 64 + tn * 16 + fr];

#pragma unroll
    for (int tm = 0; tm < 4; ++tm) {
        const int rowb = m0 + wr * 64 + tm * 16 + fq * 4;
#pragma unroll
        for (int r = 0; r < 4; ++r) {
            float s = 0.f;
#pragma unroll
            for (int tn = 0; tn < 4; ++tn) {
                const float e = acc[tm][tn][r] + bc[tn];
                out[(size_t)(rowb + r) * HDIM + n0 + wc * 64 + tn * 16 + fr] = (__bf16)e;
                s = fmaf(e, e, s);
            }
            s += __shfl_xor(s, 1);
            s += __shfl_xor(s, 2);
            s += __shfl_xor(s, 4);
            s += __shfl_xor(s, 8);
            if (fr == 0) atomicAdd(&n2[rowb + r], s);
        }
    }
}

// ---------------------------------------------------------------------------
// Batched dots GEMM (NT), BK=64, DMA-prefetch double-buffer:
//   out[b][i][j] = v.t / max(sqrt(vn2_i*tn2_j), eps)
// 128x128 tile, K=512 -> 8 steps. Batch-colocating XCD swizzle.
// ---------------------------------------------------------------------------
__global__ __launch_bounds__(256) void dots_kernel(const __bf16* __restrict__ v,
                                                   const __bf16* __restrict__ t,
                                                   const float* __restrict__ vn2,
                                                   const float* __restrict__ tn2,
                                                   float* __restrict__ out) {
    __shared__ __bf16 As[2][128 * 64];
    __shared__ __bf16 Bs[2][128 * 64];

    // L = (b&7) + 8*( j + 8*( i + 8*(b>>3) ) ) -> same-batch blocks share an XCD
    const int L  = blockIdx.x;
    const int b  = (L & 7) + ((L >> 9) << 3);
    const int j0 = ((L >> 3) & 7) * 128;
    const int i0 = ((L >> 6) & 7) * 128;

    const __bf16* vb = v + (size_t)b * SEQ * HDIM;
    const __bf16* tb = t + (size_t)b * SEQ * HDIM;

    const int tid  = threadIdx.x;
    const int lane = tid & 63;
    const int wave = tid >> 6;
    const int wr   = wave >> 1;
    const int wc   = wave & 1;
    const int fr   = lane & 15;
    const int fq   = lane >> 4;

    f32x4 acc[4][4] = {};
    const int nk = HDIM >> 6;   // 8

    stage_tile_bf16(vb, HDIM, i0, 0, As[0], tid);
    stage_tile_bf16(tb, HDIM, j0, 0, Bs[0], tid);
    __syncthreads();

    for (int ki = 0; ki < nk; ++ki) {
        if (ki + 1 < nk) {
            const int kk = (ki + 1) << 6;
            stage_tile_bf16(vb, HDIM, i0, kk, As[(ki + 1) & 1], tid);
            stage_tile_bf16(tb, HDIM, j0, kk, Bs[(ki + 1) & 1], tid);
        }
        const __bf16* Ab = As[ki & 1];
        const __bf16* Bb = Bs[ki & 1];
#pragma unroll
        for (int h = 0; h < 2; ++h) {
            bf16x8 a[4], bfr[4];
#pragma unroll
            for (int tm = 0; tm < 4; ++tm)
                a[tm] = frag_read(Ab, wr * 64 + tm * 16 + fr, h, fq);
#pragma unroll
            for (int tn = 0; tn < 4; ++tn)
                bfr[tn] = frag_read(Bb, wc * 64 + tn * 16 + fr, h, fq);
#pragma unroll
            for (int tm = 0; tm < 4; ++tm)
#pragma unroll
                for (int tn = 0; tn < 4; ++tn)
                    acc[tm][tn] = MFMA16(a[tm], bfr[tn], acc[tm][tn]);
        }
        __syncthreads();
    }

    float vr2[16];
#pragma unroll
    for (int tm = 0; tm < 4; ++tm)
#pragma unroll
        for (int r = 0; r < 4; ++r)
            vr2[tm * 4 + r] = vn2[b * SEQ + i0 + wr * 64 + tm * 16 + fq * 4 + r];

    float* outb = out + ((size_t)b << 20);
#pragma unroll
    for (int tn = 0; tn < 4; ++tn) {
        const int j     = j0 + wc * 64 + tn * 16 + fr;
        const float tj2 = tn2[b * SEQ + j];
#pragma unroll
        for (int tm = 0; tm < 4; ++tm) {
            const int ib = i0 + wr * 64 + tm * 16 + fq * 4;
#pragma unroll
            for (int r = 0; r < 4; ++r) {
                const float denom = fmaxf(sqrtf(vr2[tm * 4 + r] * tj2), 1e-8f);
                outb[(size_t)(ib + r) * SEQ + j] = acc[tm][tn][r] * __builtin_amdgcn_rcpf(denom);
            }
        }
    }
}

// ---------------------------------------------------------------------------
extern "C" void kernel_launch(void* const* d_in, const int* in_sizes, int n_in,
                              void* d_out, int out_size, void* d_ws, size_t ws_size,
                              hipStream_t stream) {
    const float* Xv = (const float*)d_in[0];
    const float* Xt = (const float*)d_in[1];
    const float* Wv = (const float*)d_in[2];
    const float* bv = (const float*)d_in[3];
    const float* Wt = (const float*)d_in[4];
    const float* bt = (const float*)d_in[5];
    float* out = (float*)d_out;

    char* ws = (char*)d_ws;
    size_t off = 0;
    __bf16* v   = (__bf16*)(ws + off); off += (size_t)MROWS * HDIM * 2;    // 16 MiB
    __bf16* t   = (__bf16*)(ws + off); off += (size_t)MROWS * HDIM * 2;    // 16 MiB
    __bf16* Xvb = (__bf16*)(ws + off); off += (size_t)MROWS * VD * 2;      // 32 MiB
    __bf16* Xtb = (__bf16*)(ws + off); off += (size_t)MROWS * TD * 2;      // 24 MiB
    __bf16* Wvb = (__bf16*)(ws + off); off += (size_t)HDIM * VD * 2;       // 1 MiB
    __bf16* Wtb = (__bf16*)(ws + off); off += (size_t)HDIM * TD * 2;       // 0.75 MiB
    float*  vn2 = (float*)(ws + off);  off += (size_t)MROWS * 4;           // 64 KiB
    float*  tn2 = (float*)(ws + off);  off += (size_t)MROWS * 4;           // 64 KiB

    hipMemsetAsync(vn2, 0, (size_t)2 * MROWS * 4, stream);

    // 0) fp32 -> bf16 streaming convert (X and W)
    conv_kernel<<<(NC_TOTAL + 255) / 256, 256, 0, stream>>>(Xv, Xt, Wv, Wt, Xvb, Xtb, Wvb, Wtb);

    // 1) projections + fused norms: 1024 swizzled blocks (512 v + 512 t)
    proj_kernel<<<1024, 256, 0, stream>>>(Xvb, Wvb, bv, Xtb, Wtb, bt, v, t, vn2, tn2);

    // 2) batched dots + normalize: 1024 swizzled blocks
    dots_kernel<<<1024, 256, 0, stream>>>(v, t, vn2, tn2, out);
}